// Round 7
// baseline (269.211 us; speedup 1.0000x reference)
//
#include <hip/hip_runtime.h>

#define EPS 1e-8f

// x (32,1,96,96,96) f32, mask (1,1,96,96,96) i32, weight (2,1,96,96,96) f32,
// bias (2,) f32 -> out (32,2) f32.
constexpr int N4   = 221184;          // 96^3 / 4 float4 elements
constexpr int TPB  = 512;             // 8 waves/block
constexpr int BPW  = 4;               // batches per wave (8*4 = 32)
constexpr int NBLK = 1024;            // fixed grid -> compile-time stride
constexpr int STR  = NBLK * 64;       // 65536 float4 index stride
constexpr size_t PARTIALS_BYTES = (size_t)NBLK * 64 * sizeof(float);  // 256 KB

// One pipeline stage: all 7 vector loads for one index step (BPW=4).
struct Stage {
    int4   mi;
    float4 w0, w1;
    float4 xv[BPW];
};

__device__ __forceinline__ void load_stage(Stage& s,
        const float4* __restrict__ x, const int4* __restrict__ mask,
        const float4* __restrict__ w, int i4, int b0)
{
    s.mi = mask[i4];
    s.w0 = w[i4];
    s.w1 = w[N4 + i4];
#pragma unroll
    for (int bb = 0; bb < BPW; ++bb)
        s.xv[bb] = x[(size_t)(b0 + bb) * N4 + i4];
}

__device__ __forceinline__ void compute_stage(const Stage& s, float (&acc)[BPW][2])
{
    const float m0 = s.mi.x ? 1.f : 0.f;
    const float m1 = s.mi.y ? 1.f : 0.f;
    const float m2 = s.mi.z ? 1.f : 0.f;
    const float m3 = s.mi.w ? 1.f : 0.f;
    const float wm0x = s.w0.x * m0, wm0y = s.w0.y * m1, wm0z = s.w0.z * m2, wm0w = s.w0.w * m3;
    const float wm1x = s.w1.x * m0, wm1y = s.w1.y * m1, wm1z = s.w1.z * m2, wm1w = s.w1.w * m3;
#pragma unroll
    for (int bb = 0; bb < BPW; ++bb) {
        const float4 xv = s.xv[bb];
        const float g0 = (fabsf(xv.x) > EPS) ? xv.x : 0.f;
        const float g1 = (fabsf(xv.y) > EPS) ? xv.y : 0.f;
        const float g2 = (fabsf(xv.z) > EPS) ? xv.z : 0.f;
        const float g3 = (fabsf(xv.w) > EPS) ? xv.w : 0.f;
        float a0 = acc[bb][0], a1 = acc[bb][1];
        a0 = fmaf(g0, wm0x, a0); a0 = fmaf(g1, wm0y, a0);
        a0 = fmaf(g2, wm0z, a0); a0 = fmaf(g3, wm0w, a0);
        a1 = fmaf(g0, wm1x, a1); a1 = fmaf(g1, wm1y, a1);
        a1 = fmaf(g2, wm1z, a1); a1 = fmaf(g3, wm1w, a1);
        acc[bb][0] = a0; acc[bb][1] = a1;
    }
}

// Fused kernel. Grid MUST be exactly NBLK blocks of 512 threads.
// Hot loop identical to R6 (best so far): 2-stage register pipeline, 8 waves
// share the block's mask/w stream, wave v owns batches [4v,4v+4).
// Epilogue: threadfence-reduction — last block to finish reduces the 64x1024
// partials and writes out. counter MUST be 0 on entry (memset node).
__global__ __launch_bounds__(TPB) void fused_partial(
    const float4* __restrict__ x, const int4* __restrict__ mask,
    const float4* __restrict__ w, const float* __restrict__ bias,
    float* __restrict__ partials, unsigned int* __restrict__ counter,
    float* __restrict__ out)
{
    const int tid  = threadIdx.x;
    const int wave = tid >> 6;
    const int lane = tid & 63;
    const int b0   = wave * BPW;
    const int bid  = blockIdx.x;
    const int i4   = bid * 64 + lane;          // [0, 65536)

    float acc[BPW][2];
#pragma unroll
    for (int bb = 0; bb < BPW; ++bb) { acc[bb][0] = 0.f; acc[bb][1] = 0.f; }

    Stage s0, s1;
    load_stage(s0, x, mask, w, i4,       b0);
    load_stage(s1, x, mask, w, i4 + STR, b0);
    compute_stage(s0, acc);
    load_stage(s0, x, mask, w, i4 + 2 * STR, b0);
    compute_stage(s1, acc);
    if (i4 + 3 * STR < N4) {                   // uniform: blocks 0..383
        load_stage(s1, x, mask, w, i4 + 3 * STR, b0);
        compute_stage(s0, acc);
        compute_stage(s1, acc);
    } else {
        compute_stage(s0, acc);
    }

#pragma unroll
    for (int bb = 0; bb < BPW; ++bb) {
#pragma unroll
        for (int c = 0; c < 2; ++c) {
            float v = acc[bb][c];
            v += __shfl_xor(v, 32, 64);
            v += __shfl_xor(v, 16, 64);
            v += __shfl_xor(v,  8, 64);
            v += __shfl_xor(v,  4, 64);
            v += __shfl_xor(v,  2, 64);
            v += __shfl_xor(v,  1, 64);
            acc[bb][c] = v;
        }
    }
    if (lane == 0) {
#pragma unroll
        for (int bb = 0; bb < BPW; ++bb) {
            partials[(size_t)((b0 + bb) * 2 + 0) * NBLK + bid] = acc[bb][0];
            partials[(size_t)((b0 + bb) * 2 + 1) * NBLK + bid] = acc[bb][1];
        }
    }

    // --- threadfence reduction: last block finalizes ---
    __threadfence();                    // release: partials visible device-wide
    __shared__ int amLast;
    if (tid == 0)
        amLast = (atomicAdd(counter, 1u) == (unsigned)(NBLK - 1));
    __syncthreads();
    if (amLast) {
        __threadfence();                // acquire: drop stale cache lines
        // 64 slots x NBLK floats (contiguous per slot). Wave v: slots
        // v, v+8, ..., v+56; per slot 64 lanes read 4 float4 each (coalesced).
        const float4* p4 = (const float4*)partials;
        for (int slot = wave; slot < 64; slot += 8) {
            float s = 0.f;
#pragma unroll
            for (int k = 0; k < 4; ++k) {
                const float4 v = p4[(size_t)slot * (NBLK / 4) + k * 64 + lane];
                s += (v.x + v.y) + (v.z + v.w);
            }
            s += __shfl_xor(s, 32, 64);
            s += __shfl_xor(s, 16, 64);
            s += __shfl_xor(s,  8, 64);
            s += __shfl_xor(s,  4, 64);
            s += __shfl_xor(s,  2, 64);
            s += __shfl_xor(s,  1, 64);
            if (lane == 0) out[slot] = s + bias[slot & 1];
        }
    }
}

// Fallbacks (only if ws_size is unexpectedly small): two-kernel path.
__global__ __launch_bounds__(256) void partial_generic(
    const float4* __restrict__ x, const int4* __restrict__ mask,
    const float4* __restrict__ w, float* __restrict__ partials)
{
    const int tid  = threadIdx.x;
    const int wave = tid >> 6;
    const int lane = tid & 63;
    const int b0   = wave * 8;

    float acc[8][2];
#pragma unroll
    for (int bb = 0; bb < 8; ++bb) { acc[bb][0] = 0.f; acc[bb][1] = 0.f; }

    const int stride = gridDim.x * 64;
    for (int i4 = blockIdx.x * 64 + lane; i4 < N4; i4 += stride) {
        const int4   mi = mask[i4];
        const float4 w0 = w[i4];
        const float4 w1 = w[N4 + i4];
        const float m0 = mi.x ? 1.f : 0.f;
        const float m1 = mi.y ? 1.f : 0.f;
        const float m2 = mi.z ? 1.f : 0.f;
        const float m3 = mi.w ? 1.f : 0.f;
        const float wm0x = w0.x * m0, wm0y = w0.y * m1, wm0z = w0.z * m2, wm0w = w0.w * m3;
        const float wm1x = w1.x * m0, wm1y = w1.y * m1, wm1z = w1.z * m2, wm1w = w1.w * m3;
#pragma unroll
        for (int bb = 0; bb < 8; ++bb) {
            const float4 xv = x[(size_t)(b0 + bb) * N4 + i4];
            const float g0 = (fabsf(xv.x) > EPS) ? xv.x : 0.f;
            const float g1 = (fabsf(xv.y) > EPS) ? xv.y : 0.f;
            const float g2 = (fabsf(xv.z) > EPS) ? xv.z : 0.f;
            const float g3 = (fabsf(xv.w) > EPS) ? xv.w : 0.f;
            float a0 = acc[bb][0], a1 = acc[bb][1];
            a0 = fmaf(g0, wm0x, a0); a0 = fmaf(g1, wm0y, a0);
            a0 = fmaf(g2, wm0z, a0); a0 = fmaf(g3, wm0w, a0);
            a1 = fmaf(g0, wm1x, a1); a1 = fmaf(g1, wm1y, a1);
            a1 = fmaf(g2, wm1z, a1); a1 = fmaf(g3, wm1w, a1);
            acc[bb][0] = a0; acc[bb][1] = a1;
        }
    }
#pragma unroll
    for (int bb = 0; bb < 8; ++bb)
#pragma unroll
        for (int c = 0; c < 2; ++c) {
            float v = acc[bb][c];
            v += __shfl_xor(v, 32, 64);
            v += __shfl_xor(v, 16, 64);
            v += __shfl_xor(v,  8, 64);
            v += __shfl_xor(v,  4, 64);
            v += __shfl_xor(v,  2, 64);
            v += __shfl_xor(v,  1, 64);
            acc[bb][c] = v;
        }
    if (lane == 0)
#pragma unroll
        for (int bb = 0; bb < 8; ++bb) {
            partials[(size_t)((b0 + bb) * 2 + 0) * gridDim.x + blockIdx.x] = acc[bb][0];
            partials[(size_t)((b0 + bb) * 2 + 1) * gridDim.x + blockIdx.x] = acc[bb][1];
        }
}

__global__ __launch_bounds__(256) void finalize_kernel(
    const float4* __restrict__ partials4, const float* __restrict__ bias,
    float* __restrict__ out, int nblk4)
{
    const int j    = blockIdx.x;
    const int tid  = threadIdx.x;
    const int wave = tid >> 6;
    const int lane = tid & 63;

    float s = 0.f;
    for (int k = tid; k < nblk4; k += 256) {
        const float4 v = partials4[(size_t)j * nblk4 + k];
        s += (v.x + v.y) + (v.z + v.w);
    }
    s += __shfl_xor(s, 32, 64);
    s += __shfl_xor(s, 16, 64);
    s += __shfl_xor(s,  8, 64);
    s += __shfl_xor(s,  4, 64);
    s += __shfl_xor(s,  2, 64);
    s += __shfl_xor(s,  1, 64);

    __shared__ float red[4];
    if (lane == 0) red[wave] = s;
    __syncthreads();
    if (tid == 0)
        out[j] = (red[0] + red[1]) + (red[2] + red[3]) + bias[j & 1];
}

extern "C" void kernel_launch(void* const* d_in, const int* in_sizes, int n_in,
                              void* d_out, int out_size, void* d_ws, size_t ws_size,
                              hipStream_t stream) {
    const float4* x    = (const float4*)d_in[0];
    const int4*   mask = (const int4*)d_in[1];
    const float4* w    = (const float4*)d_in[2];
    const float*  bias = (const float*)d_in[3];
    float* out = (float*)d_out;
    float* partials = (float*)d_ws;

    if (ws_size >= PARTIALS_BYTES + sizeof(unsigned int)) {
        unsigned int* counter =
            (unsigned int*)((char*)d_ws + PARTIALS_BYTES);
        hipMemsetAsync(counter, 0, sizeof(unsigned int), stream);
        fused_partial<<<NBLK, TPB, 0, stream>>>(x, mask, w, bias, partials,
                                                counter, out);
    } else {
        int nblk = (int)(ws_size / (64 * sizeof(float)));
        if (nblk < 4) nblk = 4;
        nblk &= ~3;
        partial_generic<<<nblk, 256, 0, stream>>>(x, mask, w, partials);
        finalize_kernel<<<64, 256, 0, stream>>>((const float4*)partials, bias,
                                                out, nblk / 4);
    }
}

// Round 8
// 26.679 us; speedup vs baseline: 10.0907x; 10.0907x over previous
//
#include <hip/hip_runtime.h>

#define EPS 1e-8f

// x (32,1,96,96,96) f32, mask (1,1,96,96,96) i32, weight (2,1,96,96,96) f32,
// bias (2,) f32 -> out (32,2) f32.
constexpr int N4    = 221184;         // 96^3 / 4 float4 elements
constexpr int TPB   = 512;            // 8 waves/block
constexpr int BPW   = 4;              // batches per wave (8*4 = 32)
constexpr int NBLK3 = 1152;           // 1152*64*3 == N4 exactly: 3 uniform steps
constexpr int STR3  = NBLK3 * 64;     // 73728
constexpr int NBLK4 = 1024;           // R6 fallback: 3 steps + conditional 4th
constexpr int STR4  = NBLK4 * 64;     // 65536

// One pipeline stage: all 7 vector loads for one index step (BPW=4).
struct Stage {
    int4   mi;
    float4 w0, w1;
    float4 xv[BPW];
};

__device__ __forceinline__ void load_stage(Stage& s,
        const float4* __restrict__ x, const int4* __restrict__ mask,
        const float4* __restrict__ w, int i4, int b0)
{
    s.mi = mask[i4];
    s.w0 = w[i4];
    s.w1 = w[N4 + i4];
#pragma unroll
    for (int bb = 0; bb < BPW; ++bb)
        s.xv[bb] = x[(size_t)(b0 + bb) * N4 + i4];
}

__device__ __forceinline__ void compute_stage(const Stage& s, float (&acc)[BPW][2])
{
    const float m0 = s.mi.x ? 1.f : 0.f;
    const float m1 = s.mi.y ? 1.f : 0.f;
    const float m2 = s.mi.z ? 1.f : 0.f;
    const float m3 = s.mi.w ? 1.f : 0.f;
    const float wm0x = s.w0.x * m0, wm0y = s.w0.y * m1, wm0z = s.w0.z * m2, wm0w = s.w0.w * m3;
    const float wm1x = s.w1.x * m0, wm1y = s.w1.y * m1, wm1z = s.w1.z * m2, wm1w = s.w1.w * m3;
#pragma unroll
    for (int bb = 0; bb < BPW; ++bb) {
        const float4 xv = s.xv[bb];
        const float g0 = (fabsf(xv.x) > EPS) ? xv.x : 0.f;
        const float g1 = (fabsf(xv.y) > EPS) ? xv.y : 0.f;
        const float g2 = (fabsf(xv.z) > EPS) ? xv.z : 0.f;
        const float g3 = (fabsf(xv.w) > EPS) ? xv.w : 0.f;
        float a0 = acc[bb][0], a1 = acc[bb][1];
        a0 = fmaf(g0, wm0x, a0); a0 = fmaf(g1, wm0y, a0);
        a0 = fmaf(g2, wm0z, a0); a0 = fmaf(g3, wm0w, a0);
        a1 = fmaf(g0, wm1x, a1); a1 = fmaf(g1, wm1y, a1);
        a1 = fmaf(g2, wm1z, a1); a1 = fmaf(g3, wm1w, a1);
        acc[bb][0] = a0; acc[bb][1] = a1;
    }
}

__device__ __forceinline__ void reduce_and_store(
        float (&acc)[BPW][2], int lane, int b0, int bid, int nblk,
        float* __restrict__ partials)
{
#pragma unroll
    for (int bb = 0; bb < BPW; ++bb) {
#pragma unroll
        for (int c = 0; c < 2; ++c) {
            float v = acc[bb][c];
            v += __shfl_xor(v, 32, 64);
            v += __shfl_xor(v, 16, 64);
            v += __shfl_xor(v,  8, 64);
            v += __shfl_xor(v,  4, 64);
            v += __shfl_xor(v,  2, 64);
            v += __shfl_xor(v,  1, 64);
            acc[bb][c] = v;
        }
    }
    if (lane == 0) {
#pragma unroll
        for (int bb = 0; bb < BPW; ++bb) {
            partials[(size_t)((b0 + bb) * 2 + 0) * nblk + bid] = acc[bb][0];
            partials[(size_t)((b0 + bb) * 2 + 1) * nblk + bid] = acc[bb][1];
        }
    }
}

// Primary hot kernel. Grid MUST be exactly NBLK3 blocks of 512 threads.
// Uniform 3 steps/lane (exact cover of N4) — no divergent 4th step, equal
// work per block for clean dispatch balancing. 2-stage register pipeline;
// NO min-waves clause (R5: capping VGPR to 32 kills MLP; R7: epilogue in
// same kernel collapses regalloc — keep this kernel minimal).
__global__ __launch_bounds__(TPB) void partial_static3(
    const float4* __restrict__ x, const int4* __restrict__ mask,
    const float4* __restrict__ w, float* __restrict__ partials)
{
    const int tid  = threadIdx.x;
    const int wave = tid >> 6;
    const int lane = tid & 63;
    const int b0   = wave * BPW;
    const int bid  = blockIdx.x;
    const int i4   = bid * 64 + lane;          // [0, 73728)

    float acc[BPW][2];
#pragma unroll
    for (int bb = 0; bb < BPW; ++bb) { acc[bb][0] = 0.f; acc[bb][1] = 0.f; }

    Stage s0, s1;
    load_stage(s0, x, mask, w, i4,        b0);
    load_stage(s1, x, mask, w, i4 + STR3, b0);
    compute_stage(s0, acc);
    load_stage(s0, x, mask, w, i4 + 2 * STR3, b0);
    compute_stage(s1, acc);
    compute_stage(s0, acc);

    reduce_and_store(acc, lane, b0, bid, NBLK3, partials);
}

// Fallback hot kernel (ws too small for 1152): exact R6 structure.
__global__ __launch_bounds__(TPB) void partial_static4(
    const float4* __restrict__ x, const int4* __restrict__ mask,
    const float4* __restrict__ w, float* __restrict__ partials)
{
    const int tid  = threadIdx.x;
    const int wave = tid >> 6;
    const int lane = tid & 63;
    const int b0   = wave * BPW;
    const int bid  = blockIdx.x;
    const int i4   = bid * 64 + lane;          // [0, 65536)

    float acc[BPW][2];
#pragma unroll
    for (int bb = 0; bb < BPW; ++bb) { acc[bb][0] = 0.f; acc[bb][1] = 0.f; }

    Stage s0, s1;
    load_stage(s0, x, mask, w, i4,        b0);
    load_stage(s1, x, mask, w, i4 + STR4, b0);
    compute_stage(s0, acc);
    load_stage(s0, x, mask, w, i4 + 2 * STR4, b0);
    compute_stage(s1, acc);
    if (i4 + 3 * STR4 < N4) {                  // uniform per block: 0..383
        load_stage(s1, x, mask, w, i4 + 3 * STR4, b0);
        compute_stage(s0, acc);
        compute_stage(s1, acc);
    } else {
        compute_stage(s0, acc);
    }

    reduce_and_store(acc, lane, b0, bid, NBLK4, partials);
}

// Last-resort generic grid-stride partial (tiny ws).
__global__ __launch_bounds__(256) void partial_generic(
    const float4* __restrict__ x, const int4* __restrict__ mask,
    const float4* __restrict__ w, float* __restrict__ partials)
{
    const int tid  = threadIdx.x;
    const int wave = tid >> 6;
    const int lane = tid & 63;
    const int b0   = wave * 8;

    float acc[8][2];
#pragma unroll
    for (int bb = 0; bb < 8; ++bb) { acc[bb][0] = 0.f; acc[bb][1] = 0.f; }

    const int stride = gridDim.x * 64;
    for (int i4 = blockIdx.x * 64 + lane; i4 < N4; i4 += stride) {
        const int4   mi = mask[i4];
        const float4 w0 = w[i4];
        const float4 w1 = w[N4 + i4];
        const float m0 = mi.x ? 1.f : 0.f;
        const float m1 = mi.y ? 1.f : 0.f;
        const float m2 = mi.z ? 1.f : 0.f;
        const float m3 = mi.w ? 1.f : 0.f;
        const float wm0x = w0.x * m0, wm0y = w0.y * m1, wm0z = w0.z * m2, wm0w = w0.w * m3;
        const float wm1x = w1.x * m0, wm1y = w1.y * m1, wm1z = w1.z * m2, wm1w = w1.w * m3;
#pragma unroll
        for (int bb = 0; bb < 8; ++bb) {
            const float4 xv = x[(size_t)(b0 + bb) * N4 + i4];
            const float g0 = (fabsf(xv.x) > EPS) ? xv.x : 0.f;
            const float g1 = (fabsf(xv.y) > EPS) ? xv.y : 0.f;
            const float g2 = (fabsf(xv.z) > EPS) ? xv.z : 0.f;
            const float g3 = (fabsf(xv.w) > EPS) ? xv.w : 0.f;
            float a0 = acc[bb][0], a1 = acc[bb][1];
            a0 = fmaf(g0, wm0x, a0); a0 = fmaf(g1, wm0y, a0);
            a0 = fmaf(g2, wm0z, a0); a0 = fmaf(g3, wm0w, a0);
            a1 = fmaf(g0, wm1x, a1); a1 = fmaf(g1, wm1y, a1);
            a1 = fmaf(g2, wm1z, a1); a1 = fmaf(g3, wm1w, a1);
            acc[bb][0] = a0; acc[bb][1] = a1;
        }
    }
#pragma unroll
    for (int bb = 0; bb < 8; ++bb)
#pragma unroll
        for (int c = 0; c < 2; ++c) {
            float v = acc[bb][c];
            v += __shfl_xor(v, 32, 64);
            v += __shfl_xor(v, 16, 64);
            v += __shfl_xor(v,  8, 64);
            v += __shfl_xor(v,  4, 64);
            v += __shfl_xor(v,  2, 64);
            v += __shfl_xor(v,  1, 64);
            acc[bb][c] = v;
        }
    if (lane == 0)
#pragma unroll
        for (int bb = 0; bb < 8; ++bb) {
            partials[(size_t)((b0 + bb) * 2 + 0) * gridDim.x + blockIdx.x] = acc[bb][0];
            partials[(size_t)((b0 + bb) * 2 + 1) * gridDim.x + blockIdx.x] = acc[bb][1];
        }
}

// Finalize: one block per output slot (64). Slot's partials are contiguous.
__global__ __launch_bounds__(256) void finalize_kernel(
    const float4* __restrict__ partials4, const float* __restrict__ bias,
    float* __restrict__ out, int nblk4)
{
    const int j    = blockIdx.x;     // slot = b*2 + c
    const int tid  = threadIdx.x;
    const int wave = tid >> 6;
    const int lane = tid & 63;

    float s = 0.f;
    for (int k = tid; k < nblk4; k += 256) {
        const float4 v = partials4[(size_t)j * nblk4 + k];
        s += (v.x + v.y) + (v.z + v.w);
    }
    s += __shfl_xor(s, 32, 64);
    s += __shfl_xor(s, 16, 64);
    s += __shfl_xor(s,  8, 64);
    s += __shfl_xor(s,  4, 64);
    s += __shfl_xor(s,  2, 64);
    s += __shfl_xor(s,  1, 64);

    __shared__ float red[4];
    if (lane == 0) red[wave] = s;
    __syncthreads();
    if (tid == 0)
        out[j] = (red[0] + red[1]) + (red[2] + red[3]) + bias[j & 1];
}

extern "C" void kernel_launch(void* const* d_in, const int* in_sizes, int n_in,
                              void* d_out, int out_size, void* d_ws, size_t ws_size,
                              hipStream_t stream) {
    const float4* x    = (const float4*)d_in[0];
    const int4*   mask = (const int4*)d_in[1];
    const float4* w    = (const float4*)d_in[2];
    const float*  bias = (const float*)d_in[3];
    float* out = (float*)d_out;
    float* partials = (float*)d_ws;

    if (ws_size >= (size_t)NBLK3 * 64 * sizeof(float)) {
        partial_static3<<<NBLK3, TPB, 0, stream>>>(x, mask, w, partials);
        finalize_kernel<<<64, 256, 0, stream>>>((const float4*)partials, bias,
                                                out, NBLK3 / 4);
    } else if (ws_size >= (size_t)NBLK4 * 64 * sizeof(float)) {
        partial_static4<<<NBLK4, TPB, 0, stream>>>(x, mask, w, partials);
        finalize_kernel<<<64, 256, 0, stream>>>((const float4*)partials, bias,
                                                out, NBLK4 / 4);
    } else {
        int nblk = (int)(ws_size / (64 * sizeof(float)));
        if (nblk < 4) nblk = 4;
        nblk &= ~3;
        partial_generic<<<nblk, 256, 0, stream>>>(x, mask, w, partials);
        finalize_kernel<<<64, 256, 0, stream>>>((const float4*)partials, bias,
                                                out, nblk / 4);
    }
}